// Round 8
// baseline (218.308 us; speedup 1.0000x reference)
//
#include <hip/hip_runtime.h>
#include <math.h>

// Problem: B,S,D = 128,256,1024 fp32; BETA = 1.0
constexpr int   Bc   = 128;
constexpr int   Sc   = 256;
constexpr int   Dc   = 1024;
constexpr float BETA = 1.0f;
constexpr int   SP   = Sc - 2;          // 254 pairs per batch
constexpr int   NP   = Bc * SP;         // 32512 pairs
constexpr int   NR   = Bc * Sc;         // 32768 rows
constexpr int   CAP  = 8;               // bucket capacity (Poisson(~1); overflow -> exact fallback)
constexpr int   RPW  = 8;               // rows per wave in k_main (consecutive, same batch)

// Workspace layout (bytes); ws is 512 MiB, we use ~4.8 MiB
constexpr size_t OFF_CNT  = 0;                                  // int[NR]
constexpr size_t OFF_REC  = 131072;                             // float4[NR*CAP] 4 MiB
constexpr size_t OFF_PPAR = OFF_REC + (size_t)NR * CAP * 16;    // float2[NP]
constexpr size_t OFF_PD   = OFF_PPAR + (size_t)NP * 8;          // float[NP]
constexpr size_t OFF_ND   = OFF_PD + (size_t)NP * 4;            // float[NP]

// ---- A: per-pair params + bucket by neg target row ----
__global__ __launch_bounds__(256) void k_build(
    const int* __restrict__ b_inx, const int* __restrict__ neg_i,
    const int* __restrict__ neg_j, int* __restrict__ cnt,
    float4* __restrict__ rec, float2* __restrict__ ppar,
    float* __restrict__ neg_dis, float* __restrict__ out)
{
    const int p = blockIdx.x * 256 + threadIdx.x;   // grid = NP/256 exactly
    if (p == 0) out[0] = 0.0f;                      // stream-ordered before k_hinge
    const int b = p / SP;
    const int j = p - b * SP;
    const int s = j + 1;
    const float th = (float)b_inx[b * Sc];
    const float tt = (float)b_inx[b * Sc + (Sc - 1)];
    const float tp = (float)b_inx[b * Sc + s];
    const float alpha = (tp - th) / (tt - th);
    const float sigma = alpha * (tt - tp);
    const float inv   = 1.0f / (2.0f * sigma * sigma);
    ppar[p] = make_float2(alpha, inv);
    const int r = neg_i[p] * Sc + neg_j[p];
    const int slot = atomicAdd(&cnt[r], 1);
    if (slot < CAP) {
        rec[r * CAP + slot] = make_float4(__int_as_float((b << 8) | j), alpha, inv, 0.0f);
    } else {
        neg_dis[p] = INFINITY;   // sentinel: k_hinge recomputes exactly
    }
}

// ---- B: single pass over bridges; each wave owns 8 consecutive rows of one batch ----
__global__ __launch_bounds__(256, 4) void k_main(
    const float* __restrict__ bridges,
    const int* __restrict__ cnt, const float4* __restrict__ rec,
    const float2* __restrict__ ppar,
    float* __restrict__ pos_dis, float* __restrict__ neg_dis)
{
    const int wid  = (blockIdx.x * 256 + threadIdx.x) >> 6;  // 0..4095
    const int lane = threadIdx.x & 63;
    const int b    = wid >> 5;            // 32 waves per batch
    const int c    = wid & 31;            // chunk within batch
    const int r0   = b * Sc + c * RPW;    // first row of this wave's chunk

    const float4* __restrict__ row4 = (const float4*)bridges;  // stride Dc/4 = 256

    // Own-batch head + (tail-head) delta, in registers for the whole chunk
    float4 h[4], dt[4];
    {
        const float4* hp = row4 + (size_t)(b * Sc) * (Dc / 4);
        const float4* tp = row4 + (size_t)(b * Sc + Sc - 1) * (Dc / 4);
#pragma unroll
        for (int k = 0; k < 4; ++k) {
            h[k] = hp[k * 64 + lane];
            const float4 t = tp[k * 64 + lane];
            dt[k] = make_float4(t.x - h[k].x, t.y - h[k].y, t.z - h[k].z, t.w - h[k].w);
        }
    }

    // First row of the stream
    float4 xc[4], xn[4];
    {
        const float4* rp = row4 + (size_t)r0 * (Dc / 4);
#pragma unroll
        for (int k = 0; k < 4; ++k) xc[k] = rp[k * 64 + lane];
    }

    for (int i = 0; i < RPW; ++i) {
        const int r = r0 + i;
        const int s = c * RPW + i;

        // Prefetch next row's stream loads before any compute
        if (i + 1 < RPW) {
            const float4* rp = row4 + (size_t)(r + 1) * (Dc / 4);
#pragma unroll
            for (int k = 0; k < 4; ++k) xn[k] = rp[k * 64 + lane];
        }

        const int nneg = min(cnt[r], CAP);
        float4 rc = rec[r * CAP];          // first record (not used if nneg==0)

        // POS role: register-only (h/dt cached)
        if (s >= 1 && s <= Sc - 2) {
            const float2 pp    = ppar[b * SP + (s - 1)];
            const float  alpha = pp.x, inv = pp.y;
            float d = 0.0f;
#pragma unroll
            for (int k = 0; k < 4; ++k) {
                const float m0 = fmaf(alpha, dt[k].x, h[k].x);
                const float m1 = fmaf(alpha, dt[k].y, h[k].y);
                const float m2 = fmaf(alpha, dt[k].z, h[k].z);
                const float m3 = fmaf(alpha, dt[k].w, h[k].w);
                const float e0 = xc[k].x - m0, e1 = xc[k].y - m1;
                const float e2 = xc[k].z - m2, e3 = xc[k].w - m3;
                d += e0 * e0 + e1 * e1 + e2 * e2 + e3 * e3;
            }
#pragma unroll
            for (int m = 32; m >= 1; m >>= 1) d += __shfl_xor(d, m);
            if (lane == 0) pos_dis[b * SP + (s - 1)] = -d * inv;
        }

        // NEG roles: pairs whose gathered neg sample is this row.
        // h_bb/t_bb loaded in 2 half-chunks to bound live VGPRs.
        for (int q = 0; q < nneg; ++q) {
            const int   e     = __float_as_int(rc.x);
            const float alpha = rc.y, inv = rc.z;
            const int   bb = e >> 8;
            const int   jj = e & 255;
            const float4* hb = row4 + (size_t)(bb * Sc) * (Dc / 4);
            const float4* tb = row4 + (size_t)(bb * Sc + Sc - 1) * (Dc / 4);
            if (q + 1 < nneg) rc = rec[r * CAP + q + 1];   // prefetch next record
            float d = 0.0f;
#pragma unroll
            for (int half = 0; half < 2; ++half) {
#pragma unroll
                for (int k = half * 2; k < half * 2 + 2; ++k) {
                    const float4 hh = hb[k * 64 + lane];
                    const float4 tt = tb[k * 64 + lane];
                    const float m0 = fmaf(alpha, tt.x - hh.x, hh.x);
                    const float m1 = fmaf(alpha, tt.y - hh.y, hh.y);
                    const float m2 = fmaf(alpha, tt.z - hh.z, hh.z);
                    const float m3 = fmaf(alpha, tt.w - hh.w, hh.w);
                    const float e0 = xc[k].x - m0, e1 = xc[k].y - m1;
                    const float e2 = xc[k].z - m2, e3 = xc[k].w - m3;
                    d += e0 * e0 + e1 * e1 + e2 * e2 + e3 * e3;
                }
            }
#pragma unroll
            for (int m = 32; m >= 1; m >>= 1) d += __shfl_xor(d, m);
            if (lane == 0) neg_dis[bb * SP + jj] = -d * inv;
        }

#pragma unroll
        for (int k = 0; k < 4; ++k) xc[k] = xn[k];
    }
}

// ---- C: hinge sum, 128 blocks, one atomicAdd per block ----
__global__ __launch_bounds__(256) void k_hinge(
    const float* __restrict__ bridges, const int* __restrict__ b_inx,
    const int* __restrict__ neg_i, const int* __restrict__ neg_j,
    const float* __restrict__ pos_dis, const float* __restrict__ neg_dis,
    float* __restrict__ out)
{
    float a = 0.0f;
    for (int p = blockIdx.x * 256 + threadIdx.x; p < NP; p += gridDim.x * 256) {
        float nd = neg_dis[p];
        if (__builtin_isinf(nd)) {
            // exact fallback for bucket overflow (expected count: 0)
            const int bb = p / SP, jj = p - bb * SP, ss = jj + 1;
            const int r  = neg_i[p] * Sc + neg_j[p];
            const float th = (float)b_inx[bb * Sc];
            const float tt = (float)b_inx[bb * Sc + (Sc - 1)];
            const float tp = (float)b_inx[bb * Sc + ss];
            const float alpha = (tp - th) / (tt - th);
            const float sigma = alpha * (tt - tp);
            const float inv   = 1.0f / (2.0f * sigma * sigma);
            const float* xr = bridges + (size_t)r * Dc;
            const float* hr = bridges + (size_t)(bb * Sc) * Dc;
            const float* tr = bridges + (size_t)(bb * Sc + Sc - 1) * Dc;
            float d = 0.0f;
            for (int k = 0; k < Dc; ++k) {
                const float h = hr[k];
                const float m = fmaf(alpha, tr[k] - h, h);
                const float e = xr[k] - m;
                d += e * e;
            }
            nd = -d * inv;
        }
        const float cur = pos_dis[p] - nd + BETA;
        if (cur > 0.0f) a += cur;
    }
    __shared__ float red[4];
#pragma unroll
    for (int m = 32; m >= 1; m >>= 1) a += __shfl_xor(a, m);
    if ((threadIdx.x & 63) == 0) red[threadIdx.x >> 6] = a;
    __syncthreads();
    if (threadIdx.x == 0) {
        const float ssum = red[0] + red[1] + red[2] + red[3];
        if (ssum != 0.0f) atomicAdd(out, ssum * (1.0f / (float)Bc));
    }
}

extern "C" void kernel_launch(void* const* d_in, const int* in_sizes, int n_in,
                              void* d_out, int out_size, void* d_ws, size_t ws_size,
                              hipStream_t stream) {
    const float* bridges = (const float*)d_in[0];
    const int*   b_inx   = (const int*)d_in[1];
    const int*   neg_i   = (const int*)d_in[2];
    const int*   neg_j   = (const int*)d_in[3];
    float*       out     = (float*)d_out;

    char* ws = (char*)d_ws;
    int*    cnt     = (int*)(ws + OFF_CNT);
    float4* rec     = (float4*)(ws + OFF_REC);
    float2* ppar    = (float2*)(ws + OFF_PPAR);
    float*  pos_dis = (float*)(ws + OFF_PD);
    float*  neg_dis = (float*)(ws + OFF_ND);

    hipMemsetAsync(cnt, 0, NR * sizeof(int), stream);
    k_build<<<NP / 256, 256, 0, stream>>>(b_inx, neg_i, neg_j, cnt, rec, ppar, neg_dis, out);
    k_main <<<NR / (64 / 64 * 4 * RPW), 256, 0, stream>>>(bridges, cnt, rec, ppar, pos_dis, neg_dis);
    k_hinge<<<128, 256, 0, stream>>>(bridges, b_inx, neg_i, neg_j, pos_dis, neg_dis, out);
}

// Round 10
// 206.102 us; speedup vs baseline: 1.0592x; 1.0592x over previous
//
#include <hip/hip_runtime.h>
#include <math.h>

// Problem: B,S,D = 128,256,1024 fp32; BETA = 1.0
constexpr int   Bc   = 128;
constexpr int   Sc   = 256;
constexpr int   Dc   = 1024;
constexpr float BETA = 1.0f;
constexpr int   SP   = Sc - 2;          // 254 pairs per batch
constexpr int   NP   = Bc * SP;         // 32512 pairs
constexpr int   NR   = Bc * Sc;         // 32768 rows
constexpr int   CAP  = 8;               // bucket capacity (Poisson(~1); overflow -> exact fallback)

// Workspace layout (bytes); ws is 512 MiB, we use ~4.8 MiB
constexpr size_t OFF_CNT  = 0;                                  // int[NR]
constexpr size_t OFF_REC  = 131072;                             // float4[NR*CAP] 4 MiB
constexpr size_t OFF_PPAR = OFF_REC + (size_t)NR * CAP * 16;    // float2[NP]
constexpr size_t OFF_PD   = OFF_PPAR + (size_t)NP * 8;          // float[NP]
constexpr size_t OFF_ND   = OFF_PD + (size_t)NP * 4;            // float[NP]

// ---- A: per-pair params + bucket by neg target row ----
__global__ __launch_bounds__(256) void k_build(
    const int* __restrict__ b_inx, const int* __restrict__ neg_i,
    const int* __restrict__ neg_j, int* __restrict__ cnt,
    float4* __restrict__ rec, float2* __restrict__ ppar,
    float* __restrict__ neg_dis, float* __restrict__ out)
{
    const int p = blockIdx.x * 256 + threadIdx.x;   // grid = NP/256 exactly
    if (p == 0) out[0] = 0.0f;                      // stream-ordered before k_hinge
    const int b = p / SP;
    const int j = p - b * SP;
    const int s = j + 1;
    const float th = (float)b_inx[b * Sc];
    const float tt = (float)b_inx[b * Sc + (Sc - 1)];
    const float tp = (float)b_inx[b * Sc + s];
    const float alpha = (tp - th) / (tt - th);
    const float sigma = alpha * (tt - tp);
    const float inv   = 1.0f / (2.0f * sigma * sigma);
    ppar[p] = make_float2(alpha, inv);
    const int r = neg_i[p] * Sc + neg_j[p];
    const int slot = atomicAdd(&cnt[r], 1);
    if (slot < CAP) {
        rec[r * CAP + slot] = make_float4(__int_as_float((b << 8) | j), alpha, inv, 0.0f);
    } else {
        neg_dis[p] = INFINITY;   // sentinel: k_hinge recomputes exactly
    }
}

// ---- B: one wave per row (32768 waves); block of 4 rows stages own-batch
//          h and dt=t-h in LDS once (4 rows always within one batch) ----
__global__ __launch_bounds__(256) void k_main(
    const float* __restrict__ bridges,
    const int* __restrict__ cnt, const float4* __restrict__ rec,
    const float2* __restrict__ ppar,
    float* __restrict__ pos_dis, float* __restrict__ neg_dis)
{
    const int tid  = threadIdx.x;
    const int wave = tid >> 6;
    const int lane = tid & 63;
    const int r    = blockIdx.x * 4 + wave;   // row id
    const int b    = r >> 8;                  // Sc = 256; block never crosses a batch
    const int s    = r & 255;

    const float4* __restrict__ row4 = (const float4*)bridges;  // stride Dc/4 = 256

    __shared__ float4 lh[256];    // head row of batch b (4 KB)
    __shared__ float4 ldt[256];   // tail-head delta   (4 KB)

    // Issue this row's stream loads FIRST so they overlap the staging loads.
    float4 x[4];
    {
        const float4* rp = row4 + (size_t)r * (Dc / 4);
#pragma unroll
        for (int k = 0; k < 4; ++k) x[k] = rp[k * 64 + lane];
    }

    // Cooperative stage: one float4 per thread per array.
    {
        const float4* hp = row4 + (size_t)(b * Sc) * (Dc / 4);
        const float4* tp = row4 + (size_t)(b * Sc + Sc - 1) * (Dc / 4);
        const float4 hv = hp[tid];
        const float4 tv = tp[tid];
        lh[tid]  = hv;
        ldt[tid] = make_float4(tv.x - hv.x, tv.y - hv.y, tv.z - hv.z, tv.w - hv.w);
    }

    // Early per-row metadata loads (overlap with staging)
    const int nneg = min(cnt[r], CAP);
    float4 rc = rec[r * CAP];                 // first record (unused if nneg==0)
    float2 pp = make_float2(0.f, 0.f);
    if (s >= 1 && s <= Sc - 2) pp = ppar[b * SP + (s - 1)];

    __syncthreads();

    // POS role: h/dt from LDS, 3 VALU/elem
    if (s >= 1 && s <= Sc - 2) {
        const float alpha = pp.x, inv = pp.y;
        float d = 0.0f;
#pragma unroll
        for (int k = 0; k < 4; ++k) {
            const float4 hk = lh[k * 64 + lane];
            const float4 dk = ldt[k * 64 + lane];
            const float m0 = fmaf(alpha, dk.x, hk.x);
            const float m1 = fmaf(alpha, dk.y, hk.y);
            const float m2 = fmaf(alpha, dk.z, hk.z);
            const float m3 = fmaf(alpha, dk.w, hk.w);
            const float e0 = x[k].x - m0, e1 = x[k].y - m1;
            const float e2 = x[k].z - m2, e3 = x[k].w - m3;
            d += e0 * e0 + e1 * e1 + e2 * e2 + e3 * e3;
        }
#pragma unroll
        for (int m = 32; m >= 1; m >>= 1) d += __shfl_xor(d, m);
        if (lane == 0) pos_dis[b * SP + (s - 1)] = -d * inv;
    }

    // NEG roles: pairs whose gathered neg sample is this row (h/t from L2)
    for (int q = 0; q < nneg; ++q) {
        const int   e     = __float_as_int(rc.x);
        const float alpha = rc.y, inv = rc.z;
        const int   bb = e >> 8;
        const int   jj = e & 255;
        const float4* hb = row4 + (size_t)(bb * Sc) * (Dc / 4);
        const float4* tb = row4 + (size_t)(bb * Sc + Sc - 1) * (Dc / 4);
        if (q + 1 < nneg) rc = rec[r * CAP + q + 1];   // prefetch next record
        float d = 0.0f;
#pragma unroll
        for (int k = 0; k < 4; ++k) {
            const float4 hh = hb[k * 64 + lane];
            const float4 tt = tb[k * 64 + lane];
            const float m0 = fmaf(alpha, tt.x - hh.x, hh.x);
            const float m1 = fmaf(alpha, tt.y - hh.y, hh.y);
            const float m2 = fmaf(alpha, tt.z - hh.z, hh.z);
            const float m3 = fmaf(alpha, tt.w - hh.w, hh.w);
            const float e0 = x[k].x - m0, e1 = x[k].y - m1;
            const float e2 = x[k].z - m2, e3 = x[k].w - m3;
            d += e0 * e0 + e1 * e1 + e2 * e2 + e3 * e3;
        }
#pragma unroll
        for (int m = 32; m >= 1; m >>= 1) d += __shfl_xor(d, m);
        if (lane == 0) neg_dis[bb * SP + jj] = -d * inv;
    }
}

// ---- C: hinge sum, 128 blocks, one atomicAdd per block ----
__global__ __launch_bounds__(256) void k_hinge(
    const float* __restrict__ bridges, const int* __restrict__ b_inx,
    const int* __restrict__ neg_i, const int* __restrict__ neg_j,
    const float* __restrict__ pos_dis, const float* __restrict__ neg_dis,
    float* __restrict__ out)
{
    float a = 0.0f;
    for (int p = blockIdx.x * 256 + threadIdx.x; p < NP; p += gridDim.x * 256) {
        float nd = neg_dis[p];
        if (__builtin_isinf(nd)) {
            // exact fallback for bucket overflow (expected count: 0)
            const int bb = p / SP, jj = p - bb * SP, ss = jj + 1;
            const int r  = neg_i[p] * Sc + neg_j[p];
            const float th = (float)b_inx[bb * Sc];
            const float tt = (float)b_inx[bb * Sc + (Sc - 1)];
            const float tp = (float)b_inx[bb * Sc + ss];
            const float alpha = (tp - th) / (tt - th);
            const float sigma = alpha * (tt - tp);
            const float inv   = 1.0f / (2.0f * sigma * sigma);
            const float* xr = bridges + (size_t)r * Dc;
            const float* hr = bridges + (size_t)(bb * Sc) * Dc;
            const float* tr = bridges + (size_t)(bb * Sc + Sc - 1) * Dc;
            float d = 0.0f;
            for (int k = 0; k < Dc; ++k) {
                const float h = hr[k];
                const float m = fmaf(alpha, tr[k] - h, h);
                const float e = xr[k] - m;
                d += e * e;
            }
            nd = -d * inv;
        }
        const float cur = pos_dis[p] - nd + BETA;
        if (cur > 0.0f) a += cur;
    }
    __shared__ float red[4];
#pragma unroll
    for (int m = 32; m >= 1; m >>= 1) a += __shfl_xor(a, m);
    if ((threadIdx.x & 63) == 0) red[threadIdx.x >> 6] = a;
    __syncthreads();
    if (threadIdx.x == 0) {
        const float ssum = red[0] + red[1] + red[2] + red[3];
        if (ssum != 0.0f) atomicAdd(out, ssum * (1.0f / (float)Bc));
    }
}

extern "C" void kernel_launch(void* const* d_in, const int* in_sizes, int n_in,
                              void* d_out, int out_size, void* d_ws, size_t ws_size,
                              hipStream_t stream) {
    const float* bridges = (const float*)d_in[0];
    const int*   b_inx   = (const int*)d_in[1];
    const int*   neg_i   = (const int*)d_in[2];
    const int*   neg_j   = (const int*)d_in[3];
    float*       out     = (float*)d_out;

    char* ws = (char*)d_ws;
    int*    cnt     = (int*)(ws + OFF_CNT);
    float4* rec     = (float4*)(ws + OFF_REC);
    float2* ppar    = (float2*)(ws + OFF_PPAR);
    float*  pos_dis = (float*)(ws + OFF_PD);
    float*  neg_dis = (float*)(ws + OFF_ND);

    hipMemsetAsync(cnt, 0, NR * sizeof(int), stream);
    k_build<<<NP / 256, 256, 0, stream>>>(b_inx, neg_i, neg_j, cnt, rec, ppar, neg_dis, out);
    k_main <<<NR / 4, 256, 0, stream>>>(bridges, cnt, rec, ppar, pos_dis, neg_dis);
    k_hinge<<<128, 256, 0, stream>>>(bridges, b_inx, neg_i, neg_j, pos_dis, neg_dis, out);
}